// Round 7
// baseline (1147.021 us; speedup 1.0000x reference)
//
#include <hip/hip_runtime.h>
#include <hip/hip_cooperative_groups.h>
#include <cstdint>
#include <cstddef>

namespace cg = cooperative_groups;

#define NEG_SLOPE 0.2f
#define LOG2E 1.44269504f
#define SMEM_BYTES 17408      // union LDS: gemm Bs (64*136*2) is the max

typedef __attribute__((ext_vector_type(8))) short short8;   // 8 bf16 (4 VGPRs)
typedef __attribute__((ext_vector_type(4))) float f32x4;    // MFMA accumulator

__device__ __forceinline__ float bf2f(unsigned short u) {
    union { unsigned int i; float f; } x; x.i = ((unsigned int)u) << 16; return x.f;
}
__device__ __forceinline__ unsigned short f2bf(float f) {
    union { float f; unsigned int i; } x;
    x.f = f;
    unsigned int u = x.i;
    return (unsigned short)((u + 0x7FFFu + ((u >> 16) & 1u)) >> 16);   // RNE
}

// 8-lane sum via DPP (VALU pipe): xor1, xor2 quad_perms, row_half_mirror.
__device__ __forceinline__ float dpp_sum8(float p) {
    p += __int_as_float(__builtin_amdgcn_update_dpp(0, __float_as_int(p), 0xB1, 0xF, 0xF, true));  // quad_perm [1,0,3,2]
    p += __int_as_float(__builtin_amdgcn_update_dpp(0, __float_as_int(p), 0x4E, 0xF, 0xF, true));  // quad_perm [2,3,0,1]
    p += __int_as_float(__builtin_amdgcn_update_dpp(0, __float_as_int(p), 0x141, 0xF, 0xF, true)); // row_half_mirror
    return p;
}

// =====================================================================
// All pointers/sizes in one struct so the cooperative launch takes one arg.
// =====================================================================
struct KParams {
    const float* x; const int* srcI; const int* dstI; const int* batch; const float* meta;
    const float *Wl0, *bl0, *Wr0, *br0, *att0, *b0;
    const float *Wl1, *bl1, *Wr1, *br1, *att1, *b1;
    const float *Wl2, *bl2, *Wr2, *br2, *att2, *b2;
    const float *Wh1, *bh1, *Wh2, *bh2;
    float* out;
    unsigned short *xlbuf, *xrbuf, *hbuf, *csr_src, *Bt0, *Bt1, *Bt2;
    int *rowptr, *hist_g, *hist_s, *bsum;
    unsigned int* sorted;
    int N, E, B, tile;
};

// ===================== phase device functions =========================

// P0: weight prep (grid-stride) + coarse histogram (blocks < 256).
__device__ __forceinline__ void phase_prep_hist(const KParams& p, unsigned char* smem) {
    const int t = threadIdx.x;
    int* h = (int*)smem;
    if (blockIdx.x < 256) {                        // block-uniform
        h[t] = 0;
        __syncthreads();
        const int e0 = blockIdx.x * p.tile;
        const int e1 = min(p.E, e0 + p.tile);
        for (int e = e0 + t; e < e1; e += 256)
            atomicAdd(&h[p.dstI[e] >> 8], 1);
        __syncthreads();
        p.hist_g[t * 256 + blockIdx.x] = h[t];
    }
    const int SZ = 256 * 128;
    for (int idx0 = blockIdx.x * 256 + t; idx0 < 2 * SZ + 64 * 128; idx0 += gridDim.x * 256) {
        int idx = idx0;
        const float *Wl, *Wr; unsigned short* Bt; int dout;
        if (idx < SZ)          { Wl = p.Wl0; Wr = p.Wr0; Bt = p.Bt0; dout = 128; }
        else if (idx < 2 * SZ) { Wl = p.Wl1; Wr = p.Wr1; Bt = p.Bt1; dout = 128; idx -= SZ; }
        else                   { Wl = p.Wl2; Wr = p.Wr2; Bt = p.Bt2; dout = 32;  idx -= 2 * SZ; }
        int n = idx >> 7, k = idx & 127;
        float v = (n < dout) ? Wl[(size_t)k * dout + n] : Wr[(size_t)k * dout + (n - dout)];
        Bt[idx] = f2bf(v);
    }
}

// P1a: blocks 0..31 locally scan their 2048-entry chunk of hist_g into
// hist_s (no global base) and emit chunk totals to bsum.
__device__ __forceinline__ void phase_scanA(const KParams& p, unsigned char* smem) {
    if (blockIdx.x >= 32) return;
    int* sdat = (int*)smem;               // 2048 ints
    int* tsum = (int*)(smem + 8192);      // 256 ints
    const int t = threadIdx.x;
    const int base = blockIdx.x * 2048;
#pragma unroll
    for (int i = 0; i < 8; ++i) sdat[t + i * 256] = p.hist_g[base + t + i * 256];
    __syncthreads();
    int vals[8]; int s = 0;
#pragma unroll
    for (int j = 0; j < 8; ++j) { vals[j] = sdat[t * 8 + j]; s += vals[j]; }
    tsum[t] = s;
    __syncthreads();
    for (int off = 1; off < 256; off <<= 1) {
        int u = (t >= off) ? tsum[t - off] : 0;
        __syncthreads();
        tsum[t] += u;
        __syncthreads();
    }
    if (t == 0) p.bsum[blockIdx.x] = tsum[255];
    int run = tsum[t] - s;
#pragma unroll
    for (int j = 0; j < 8; ++j) { sdat[t * 8 + j] = run; run += vals[j]; }
    __syncthreads();
#pragma unroll
    for (int i = 0; i < 8; ++i) p.hist_s[base + t + i * 256] = sdat[t + i * 256];
}

// P1b: block 0 exclusive-scans the 32 chunk totals.
__device__ __forceinline__ void phase_scanB(const KParams& p) {
    const int t = threadIdx.x;
    if (blockIdx.x == 0 && t < 32) {
        int o = p.bsum[t];
        int v = o;
#pragma unroll
        for (int off = 1; off < 32; off <<= 1) {
            int u = __shfl_up(v, off);
            if (t >= off) v += u;
        }
        p.bsum[t] = v - o;                // exclusive
    }
}

// P1c: blocks 0..31 add their chunk base.
__device__ __forceinline__ void phase_scanC(const KParams& p) {
    if (blockIdx.x >= 32) return;
    const int t = threadIdx.x;
    const int add = p.bsum[blockIdx.x];
    const int base = blockIdx.x * 2048;
#pragma unroll
    for (int i = 0; i < 8; ++i) p.hist_s[base + t + i * 256] += add;
}

// P2: scatter into coarse-sorted order (blocks < 256, LDS cursors).
__device__ __forceinline__ void phase_scatter(const KParams& p, unsigned char* smem) {
    if (blockIdx.x >= 256) return;
    int* cur = (int*)smem;
    const int t = threadIdx.x;
    cur[t] = p.hist_s[t * 256 + blockIdx.x];
    __syncthreads();
    const int e0 = blockIdx.x * p.tile;
    const int e1 = min(p.E, e0 + p.tile);
    for (int e = e0 + t; e < e1; e += 256) {
        int d = p.dstI[e];
        int pos = atomicAdd(&cur[d >> 8], 1);
        p.sorted[pos] = ((unsigned int)d << 16) | (unsigned int)p.srcI[e];
    }
}

// P3: per coarse bucket fine hist + LDS scan -> rowptr + csr_src.
__device__ __forceinline__ void phase_fine(const KParams& p, unsigned char* smem) {
    int* h  = (int*)smem;
    int* sc = (int*)(smem + 1024);
    const int t = threadIdx.x;
    const int nb = (p.N >> 8) + 1;
    for (int d = blockIdx.x; d < nb; d += gridDim.x) {
        __syncthreads();
        const int start = p.hist_s[d * 256];
        const int end   = (d < 255) ? p.hist_s[(d + 1) * 256] : p.E;
        h[t] = 0;
        __syncthreads();
        for (int e = start + t; e < end; e += 256)
            atomicAdd(&h[(p.sorted[e] >> 16) & 0xFF], 1);
        __syncthreads();
        int v = h[t];
        sc[t] = v;
        __syncthreads();
        for (int off = 1; off < 256; off <<= 1) {
            int u = (t >= off) ? sc[t - off] : 0;
            __syncthreads();
            sc[t] += u;
            __syncthreads();
        }
        const int base = start + sc[t] - v;
        const int node = (d << 8) + t;
        if (node <= p.N) p.rowptr[node] = base;
        h[t] = base;
        __syncthreads();
        for (int e = start + t; e < end; e += 256) {
            unsigned int it = p.sorted[e];
            int pos = atomicAdd(&h[(it >> 16) & 0xFF], 1);
            p.csr_src[pos] = (unsigned short)(it & 0xFFFFu);
        }
    }
}

// gemm phase (r4-proven body, BN=64, grid-stride over tiles).
__device__ __forceinline__ void gemm_phase(
    const void* Avoid, int M, bool abf16,
    const unsigned short* __restrict__ Bt,
    const float* __restrict__ bl, const float* __restrict__ br,
    int dout, int lognyt, unsigned short* __restrict__ XL, unsigned short* __restrict__ XR,
    unsigned char* smem)
{
    unsigned short* Bs = (unsigned short*)smem;    // [64][136]
    const int t    = threadIdx.x;
    const int w    = t >> 6;
    const int lane = t & 63;
    const int fr   = lane & 15;
    const int quad = lane >> 4;
    const int mb = (M + 63) >> 6;
    const int ntiles = mb << lognyt;
    const int nymask = (1 << lognyt) - 1;

    for (int tid = blockIdx.x; tid < ntiles; tid += gridDim.x) {
        const int m0 = (tid >> lognyt) * 64;
        const int n0 = (tid & nymask) * 64;
        __syncthreads();                            // Bs WAR across tiles
#pragma unroll
        for (int i = 0; i < 4; ++i) {
            int c  = t + i * 256;
            int n  = c >> 4;
            int kc = (c & 15) * 8;
            *(short8*)(Bs + n * 136 + kc) =
                *(const short8*)(Bt + (size_t)(n0 + n) * 128 + kc);
        }
        const int arow = m0 + w * 16 + fr;
        const size_t abase = (size_t)(arow < M ? arow : 0) * 128 + quad * 8;
        short8 afr[4];
        if (abf16) {
            const unsigned short* A = (const unsigned short*)Avoid;
#pragma unroll
            for (int kk = 0; kk < 4; ++kk)
                afr[kk] = *(const short8*)(A + abase + kk * 32);
        } else {
            const float* A = (const float*)Avoid;
#pragma unroll
            for (int kk = 0; kk < 4; ++kk) {
                float4 lo = *(const float4*)(A + abase + kk * 32);
                float4 hi = *(const float4*)(A + abase + kk * 32 + 4);
                afr[kk][0] = (short)f2bf(lo.x); afr[kk][1] = (short)f2bf(lo.y);
                afr[kk][2] = (short)f2bf(lo.z); afr[kk][3] = (short)f2bf(lo.w);
                afr[kk][4] = (short)f2bf(hi.x); afr[kk][5] = (short)f2bf(hi.y);
                afr[kk][6] = (short)f2bf(hi.z); afr[kk][7] = (short)f2bf(hi.w);
            }
        }
        __syncthreads();

        f32x4 acc[4] = {};
        const unsigned short* bp = Bs + fr * 136 + quad * 8;
#pragma unroll
        for (int kk = 0; kk < 4; ++kk) {
#pragma unroll
            for (int j = 0; j < 4; ++j) {
                short8 bfr = *(const short8*)(bp + j * 16 * 136 + kk * 32);
                acc[j] = __builtin_amdgcn_mfma_f32_16x16x32_bf16(afr[kk], bfr, acc[j], 0, 0, 0);
            }
        }
#pragma unroll
        for (int j = 0; j < 4; ++j) {
            int col = n0 + j * 16 + fr;
            float bias = (col < dout) ? bl[col] : br[col - dout];
#pragma unroll
            for (int r = 0; r < 4; ++r) {
                int row = m0 + w * 16 + quad * 4 + r;
                if (row < M) {
                    unsigned short o = f2bf(acc[j][r] + bias);
                    if (col < dout) XL[(size_t)row * dout + col] = o;
                    else            XR[(size_t)row * dout + (col - dout)] = o;
                }
            }
        }
    }
}

// gat phase (r5-proven body, grid-stride over 4-node groups, no LDS).
template<int H>
__device__ __forceinline__ void gat_phase(
    const unsigned short* __restrict__ xl, const unsigned short* __restrict__ xr,
    const int* __restrict__ rowptr, const unsigned short* __restrict__ csr_src,
    const float* __restrict__ att, const float* __restrict__ bias,
    unsigned short* __restrict__ hout, int hstride, int N)
{
    constexpr int HC  = 32 * H;
    constexpr int LPE = HC / 4;
    constexpr int EPW = 64 / LPE;
    const int ngrp = (N + 3) >> 2;
    for (int grp = blockIdx.x; grp < ngrp; grp += gridDim.x) {
        const int node = grp * 4 + (threadIdx.x >> 6);
        if (node >= N) continue;
        const int lane = threadIdx.x & 63;
        const int q    = lane % LPE;
        const int slot = lane / LPE;
        const int rs   = rowptr[node];
        const int re   = rowptr[node + 1];

        const unsigned short* __restrict__ xlb = xl + 4 * q;
        float4 xri;
        {
            ushort4 u = *(const ushort4*)(xr + (size_t)node * HC + 4 * q);
            xri.x = bf2f(u.x); xri.y = bf2f(u.y); xri.z = bf2f(u.z); xri.w = bf2f(u.w);
        }
        float4 b1, b2;
        {
            float4 a = *(const float4*)(att + 4 * q);
            const float c1 = 0.5f * (1.0f + NEG_SLOPE) * LOG2E;
            const float c2 = 0.5f * (1.0f - NEG_SLOPE) * LOG2E;
            b1.x = a.x * c1; b1.y = a.y * c1; b1.z = a.z * c1; b1.w = a.w * c1;
            b2.x = a.x * c2; b2.y = a.y * c2; b2.z = a.z * c2; b2.w = a.w * c2;
        }

        float l = 0.f;
        float4 acc = make_float4(0.f, 0.f, 0.f, 0.f);

        auto ld4 = [&](int s) -> float4 {
            ushort4 u = *(const ushort4*)(xlb + (size_t)s * HC);
            float4 v;
            v.x = bf2f(u.x); v.y = bf2f(u.y); v.z = bf2f(u.z); v.w = bf2f(u.w);
            return v;
        };
        auto edge_w = [&](const float4& v) -> float {
            float sx = v.x + xri.x, sy = v.y + xri.y, sz = v.z + xri.z, sw = v.w + xri.w;
            float p  = b1.x * sx;
            float pq = b2.x * fabsf(sx);
            p  = fmaf(b1.y, sy, p);
            pq = fmaf(b2.y, fabsf(sy), pq);
            p  = fmaf(b1.z, sz, p);
            pq = fmaf(b2.z, fabsf(sz), pq);
            p  = fmaf(b1.w, sw, p);
            pq = fmaf(b2.w, fabsf(sw), pq);
            p += pq;
            p = dpp_sum8(p);
            return exp2f(p);
        };

        if (slot == 0) {
            float4 v = ld4(node);
            float w = edge_w(v);
            l = w;
            acc.x = w * v.x; acc.y = w * v.y; acc.z = w * v.z; acc.w = w * v.w;
        }
        int k = rs + slot;
        for (; k + EPW < re; k += 2 * EPW) {
            int s0 = csr_src[k];
            int s1 = csr_src[k + EPW];
            float4 v0 = ld4(s0);
            float4 v1 = ld4(s1);
            float w0 = edge_w(v0);
            float w1 = edge_w(v1);
            l += w0 + w1;
            acc.x = fmaf(w0, v0.x, fmaf(w1, v1.x, acc.x));
            acc.y = fmaf(w0, v0.y, fmaf(w1, v1.y, acc.y));
            acc.z = fmaf(w0, v0.z, fmaf(w1, v1.z, acc.z));
            acc.w = fmaf(w0, v0.w, fmaf(w1, v1.w, acc.w));
        }
        if (k < re) {
            int s0 = csr_src[k];
            float4 v0 = ld4(s0);
            float w0 = edge_w(v0);
            l += w0;
            acc.x = fmaf(w0, v0.x, acc.x);
            acc.y = fmaf(w0, v0.y, acc.y);
            acc.z = fmaf(w0, v0.z, acc.z);
            acc.w = fmaf(w0, v0.w, acc.w);
        }
#pragma unroll
        for (int mask = LPE; mask < 64; mask <<= 1) {
            l     += __shfl_xor(l, mask);
            acc.x += __shfl_xor(acc.x, mask);
            acc.y += __shfl_xor(acc.y, mask);
            acc.z += __shfl_xor(acc.z, mask);
            acc.w += __shfl_xor(acc.w, mask);
        }
        if (lane < LPE) {
            const float4 bi = *(const float4*)(bias + 4 * q);
            float inv = 1.f / (l + 1e-16f);
            float4 o;
            o.x = acc.x * inv + bi.x;
            o.y = acc.y * inv + bi.y;
            o.z = acc.z * inv + bi.z;
            o.w = acc.w * inv + bi.w;
            o.x = (o.x > 0.f) ? o.x : expm1f(o.x);
            o.y = (o.y > 0.f) ? o.y : expm1f(o.y);
            o.z = (o.z > 0.f) ? o.z : expm1f(o.z);
            o.w = (o.w > 0.f) ? o.w : expm1f(o.w);
            ushort4 ob;
            ob.x = f2bf(o.x); ob.y = f2bf(o.y); ob.z = f2bf(o.z); ob.w = f2bf(o.w);
            *(ushort4*)(hout + (size_t)node * hstride + 4 * q) = ob;
        }
    }
}

// pool+head phase: 256-thread blocks handle 2 graphs (128 threads each).
__device__ __forceinline__ void pool_phase(const KParams& p, unsigned char* smem) {
    float* s = (float*)smem;              // 256 floats
    float* z = (float*)(smem + 1024);     // 2 x 44 floats
    const int t    = threadIdx.x;
    const int half = t >> 7;
    const int tl   = t & 127;
    for (int g0 = blockIdx.x * 2; g0 < p.B; g0 += gridDim.x * 2) {
        __syncthreads();                  // reuse across iterations
        const int b = g0 + half;
        const bool active = b < p.B;
        int start = 0, end = 0;
        if (active) {
            int lo = 0, hi = p.N;
            while (lo < hi) { int mid = (lo + hi) >> 1; if (p.batch[mid] < b) lo = mid + 1; else hi = mid; }
            int lo2 = lo, hi2 = p.N;
            while (lo2 < hi2) { int mid = (lo2 + hi2) >> 1; if (p.batch[mid] < b + 1) lo2 = mid + 1; else hi2 = mid; }
            start = lo; end = lo2;
        }
        const int c = tl & 31, r = tl >> 5;
        float acc = 0.f;
        for (int row = start + r; row < end; row += 4)
            acc += bf2f(p.hbuf[(size_t)row * 32 + c]);
        s[t] = acc;
        __syncthreads();
        if (tl < 32) {
            float sum = s[half * 128 + tl] + s[half * 128 + tl + 32]
                      + s[half * 128 + tl + 64] + s[half * 128 + tl + 96];
            z[half * 44 + tl] = sum / fmaxf((float)(end - start), 1.0f);
        } else if (tl < 44 && active) {
            z[half * 44 + tl] = p.meta[(size_t)b * 12 + (tl - 32)];
        }
        __syncthreads();
        if (tl < 32 && active) {
            float hj = p.bh1[tl];
#pragma unroll
            for (int k = 0; k < 44; ++k)
                hj = fmaf(z[half * 44 + k], p.Wh1[k * 32 + tl], hj);
            hj = fmaxf(hj, 0.f);
            float pr = hj * p.Wh2[tl];
#pragma unroll
            for (int off = 16; off >= 1; off >>= 1)
                pr += __shfl_xor(pr, off, 32);
            if (tl == 0) p.out[b] = pr + p.bh2[0];
        }
    }
}

// ===================== the cooperative mega-kernel ====================
__global__ __launch_bounds__(256) void mega(KParams p) {
    cg::grid_group gg = cg::this_grid();
    __shared__ __attribute__((aligned(16))) unsigned char smem[SMEM_BYTES];

    phase_prep_hist(p, smem);                                   gg.sync();
    phase_scanA(p, smem);                                       gg.sync();
    phase_scanB(p);                                             gg.sync();
    phase_scanC(p);                                             gg.sync();
    phase_scatter(p, smem);                                     gg.sync();
    phase_fine(p, smem);                                        gg.sync();
    gemm_phase(p.x,    p.N, false, p.Bt0, p.bl0, p.br0, 128, 2, p.xlbuf, p.xrbuf, smem); gg.sync();
    gat_phase<4>(p.xlbuf, p.xrbuf, p.rowptr, p.csr_src, p.att0, p.b0, p.hbuf, 128, p.N); gg.sync();
    gemm_phase(p.hbuf, p.N, true,  p.Bt1, p.bl1, p.br1, 128, 2, p.xlbuf, p.xrbuf, smem); gg.sync();
    gat_phase<4>(p.xlbuf, p.xrbuf, p.rowptr, p.csr_src, p.att1, p.b1, p.hbuf, 128, p.N); gg.sync();
    gemm_phase(p.hbuf, p.N, true,  p.Bt2, p.bl2, p.br2, 32,  0, p.xlbuf, p.xrbuf, smem); gg.sync();
    gat_phase<1>(p.xlbuf, p.xrbuf, p.rowptr, p.csr_src, p.att2, p.b2, p.hbuf, 32,  p.N); gg.sync();
    pool_phase(p, smem);
}

// ===================== fallback wrappers (normal launches) ============
__global__ __launch_bounds__(256) void fb_p0(KParams p) {
    __shared__ __attribute__((aligned(16))) unsigned char smem[SMEM_BYTES];
    phase_prep_hist(p, smem);
}
__global__ __launch_bounds__(256) void fb_scanA(KParams p) {
    __shared__ __attribute__((aligned(16))) unsigned char smem[SMEM_BYTES];
    phase_scanA(p, smem);
}
__global__ __launch_bounds__(256) void fb_scanB(KParams p) { phase_scanB(p); }
__global__ __launch_bounds__(256) void fb_scanC(KParams p) { phase_scanC(p); }
__global__ __launch_bounds__(256) void fb_scatter(KParams p) {
    __shared__ __attribute__((aligned(16))) unsigned char smem[SMEM_BYTES];
    phase_scatter(p, smem);
}
__global__ __launch_bounds__(256) void fb_fine(KParams p) {
    __shared__ __attribute__((aligned(16))) unsigned char smem[SMEM_BYTES];
    phase_fine(p, smem);
}
__global__ __launch_bounds__(256) void fb_gemm(KParams p, int layer) {
    __shared__ __attribute__((aligned(16))) unsigned char smem[SMEM_BYTES];
    if (layer == 0)      gemm_phase(p.x,    p.N, false, p.Bt0, p.bl0, p.br0, 128, 2, p.xlbuf, p.xrbuf, smem);
    else if (layer == 1) gemm_phase(p.hbuf, p.N, true,  p.Bt1, p.bl1, p.br1, 128, 2, p.xlbuf, p.xrbuf, smem);
    else                 gemm_phase(p.hbuf, p.N, true,  p.Bt2, p.bl2, p.br2, 32,  0, p.xlbuf, p.xrbuf, smem);
}
__global__ __launch_bounds__(256) void fb_gat4(KParams p, int layer) {
    if (layer == 0) gat_phase<4>(p.xlbuf, p.xrbuf, p.rowptr, p.csr_src, p.att0, p.b0, p.hbuf, 128, p.N);
    else            gat_phase<4>(p.xlbuf, p.xrbuf, p.rowptr, p.csr_src, p.att1, p.b1, p.hbuf, 128, p.N);
}
__global__ __launch_bounds__(256) void fb_gat1(KParams p) {
    gat_phase<1>(p.xlbuf, p.xrbuf, p.rowptr, p.csr_src, p.att2, p.b2, p.hbuf, 32, p.N);
}
__global__ __launch_bounds__(256) void fb_pool(KParams p) {
    __shared__ __attribute__((aligned(16))) unsigned char smem[SMEM_BYTES];
    pool_phase(p, smem);
}

// =====================================================================
extern "C" void kernel_launch(void* const* d_in, const int* in_sizes, int n_in,
                              void* d_out, int out_size, void* d_ws, size_t ws_size,
                              hipStream_t stream)
{
    const int N  = in_sizes[0] / 128;
    const int E  = in_sizes[1] / 2;
    const int B  = in_sizes[3] / 12;

    char* wsp = (char*)d_ws;
    size_t off_ = 0;
    auto alloc = [&](size_t bytes) {
        char* ptr = wsp + off_;
        off_ = (off_ + bytes + 255) & ~(size_t)255;
        return ptr;
    };

    KParams p;
    p.x     = (const float*)d_in[0];
    p.srcI  = (const int*)d_in[1];
    p.dstI  = (const int*)d_in[1] + E;
    p.batch = (const int*)d_in[2];
    p.meta  = (const float*)d_in[3];
    p.Wl0 = (const float*)d_in[4];  p.bl0 = (const float*)d_in[5];
    p.Wr0 = (const float*)d_in[6];  p.br0 = (const float*)d_in[7];
    p.att0 = (const float*)d_in[8]; p.b0  = (const float*)d_in[9];
    p.Wl1 = (const float*)d_in[10]; p.bl1 = (const float*)d_in[11];
    p.Wr1 = (const float*)d_in[12]; p.br1 = (const float*)d_in[13];
    p.att1 = (const float*)d_in[14]; p.b1 = (const float*)d_in[15];
    p.Wl2 = (const float*)d_in[16]; p.bl2 = (const float*)d_in[17];
    p.Wr2 = (const float*)d_in[18]; p.br2 = (const float*)d_in[19];
    p.att2 = (const float*)d_in[20]; p.b2 = (const float*)d_in[21];
    p.Wh1 = (const float*)d_in[22]; p.bh1 = (const float*)d_in[23];
    p.Wh2 = (const float*)d_in[24]; p.bh2 = (const float*)d_in[25];
    p.out = (float*)d_out;

    p.xlbuf  = (unsigned short*)alloc((size_t)N * 128 * 2);
    p.xrbuf  = (unsigned short*)alloc((size_t)N * 128 * 2);
    p.hbuf   = (unsigned short*)alloc((size_t)N * 128 * 2);
    p.rowptr = (int*)alloc((size_t)(N + 1) * 4);
    p.csr_src = (unsigned short*)alloc((size_t)E * 2);
    p.sorted  = (unsigned int*)alloc((size_t)E * 4);
    p.hist_g  = (int*)alloc((size_t)65536 * 4);
    p.hist_s  = (int*)alloc((size_t)65537 * 4);
    p.bsum    = (int*)alloc((size_t)256 * 4);
    p.Bt0     = (unsigned short*)alloc((size_t)256 * 128 * 2);
    p.Bt1     = (unsigned short*)alloc((size_t)256 * 128 * 2);
    p.Bt2     = (unsigned short*)alloc((size_t)64 * 128 * 2);
    p.N = N; p.E = E; p.B = B;
    p.tile = (E + 255) / 256;

    // ---- cooperative grid size from occupancy (co-residency guaranteed)
    int occ = 0;
    hipError_t qe = hipOccupancyMaxActiveBlocksPerMultiprocessor(
        &occ, reinterpret_cast<const void*>(&mega), 256, 0);
    if (qe != hipSuccess || occ < 1) occ = 2;
    int G = 256 * occ;                 // 256 CUs on MI355X
    if (G > 2048) G = 2048;
    if (G < 256)  G = 256;             // phase structure needs >= 256 blocks

    void* args[] = { (void*)&p };
    hipError_t le = hipLaunchCooperativeKernel(
        reinterpret_cast<void*>(&mega), dim3(G), dim3(256), args, 0, stream);

    if (le != hipSuccess) {
        // -------- fallback: same phases as 13 plain launches (r5-like) --------
        const int ngemm = ((N + 63) / 64) * 4;
        const int ngat  = (N + 3) / 4;
        fb_p0<<<288, 256, 0, stream>>>(p);
        fb_scanA<<<32, 256, 0, stream>>>(p);
        fb_scanB<<<1, 256, 0, stream>>>(p);
        fb_scanC<<<32, 256, 0, stream>>>(p);
        fb_scatter<<<256, 256, 0, stream>>>(p);
        fb_fine<<<(N >> 8) + 1, 256, 0, stream>>>(p);
        fb_gemm<<<ngemm, 256, 0, stream>>>(p, 0);
        fb_gat4<<<ngat, 256, 0, stream>>>(p, 0);
        fb_gemm<<<ngemm, 256, 0, stream>>>(p, 1);
        fb_gat4<<<ngat, 256, 0, stream>>>(p, 1);
        fb_gemm<<<ngemm, 256, 0, stream>>>(p, 2);
        fb_gat1<<<ngat, 256, 0, stream>>>(p);
        fb_pool<<<(B + 1) / 2, 256, 0, stream>>>(p);
    }
}

// Round 8
// 342.385 us; speedup vs baseline: 3.3501x; 3.3501x over previous
//
#include <hip/hip_runtime.h>
#include <cstdint>
#include <cstddef>

#define NEG_SLOPE 0.2f
#define LOG2E 1.44269504f
#define NBLK 256              // CSR sort: blocks in hist/scatter passes

typedef __attribute__((ext_vector_type(8))) short short8;   // 8 bf16 (4 VGPRs)
typedef __attribute__((ext_vector_type(4))) float f32x4;    // MFMA accumulator

__device__ __forceinline__ float bf2f(unsigned short u) {
    union { unsigned int i; float f; } x; x.i = ((unsigned int)u) << 16; return x.f;
}
__device__ __forceinline__ unsigned short f2bf(float f) {
    union { float f; unsigned int i; } x;
    x.f = f;
    unsigned int u = x.i;
    return (unsigned short)((u + 0x7FFFu + ((u >> 16) & 1u)) >> 16);   // RNE
}

// 8-lane sum via DPP (VALU pipe): xor1, xor2 quad_perms, row_half_mirror.
__device__ __forceinline__ float dpp_sum8(float p) {
    p += __int_as_float(__builtin_amdgcn_update_dpp(0, __float_as_int(p), 0xB1, 0xF, 0xF, true));  // quad_perm [1,0,3,2]
    p += __int_as_float(__builtin_amdgcn_update_dpp(0, __float_as_int(p), 0x4E, 0xF, 0xF, true));  // quad_perm [2,3,0,1]
    p += __int_as_float(__builtin_amdgcn_update_dpp(0, __float_as_int(p), 0x141, 0xF, 0xF, true)); // row_half_mirror
    return p;
}

// =====================================================================
// FUSED: weight prep (all 3 layers) + CSR coarse histogram (blocks<256).
// Grid = 288 blocks (prep range = 73728 elems). Proven in r6.
// =====================================================================
__global__ __launch_bounds__(256) void prep_and_hist(
    const float* __restrict__ Wl0, const float* __restrict__ Wr0,
    const float* __restrict__ Wl1, const float* __restrict__ Wr1,
    const float* __restrict__ Wl2, const float* __restrict__ Wr2,
    unsigned short* __restrict__ Bt0, unsigned short* __restrict__ Bt1,
    unsigned short* __restrict__ Bt2,
    const int* __restrict__ dst, int E, int tile, int* __restrict__ hist)
{
    __shared__ int h[256];
    const int t = threadIdx.x;
    const int b = blockIdx.x;
    if (b < NBLK) {                       // block-uniform branch: barriers safe
        h[t] = 0;
        __syncthreads();
        const int e0 = b * tile;
        const int e1 = min(E, e0 + tile);
        for (int e = e0 + t; e < e1; e += 256)
            atomicAdd(&h[dst[e] >> 8], 1);
        __syncthreads();
        hist[t * NBLK + b] = h[t];
    }
    // ---- weight prep
    int idx = b * 256 + t;
    const int SZ = 256 * 128;     // layer0/1 table elems
    const float *Wl, *Wr; unsigned short* Bt; int dout;
    if (idx < SZ)              { Wl = Wl0; Wr = Wr0; Bt = Bt0; dout = 128; }
    else if (idx < 2 * SZ)     { Wl = Wl1; Wr = Wr1; Bt = Bt1; dout = 128; idx -= SZ; }
    else if (idx < 2 * SZ + 64 * 128) { Wl = Wl2; Wr = Wr2; Bt = Bt2; dout = 32; idx -= 2 * SZ; }
    else return;
    int n = idx >> 7, k = idx & 127;
    float v = (n < dout) ? Wl[(size_t)k * dout + n] : Wr[(size_t)k * dout + (n - dout)];
    Bt[idx] = f2bf(v);
}

// =====================================================================
// Scan of the 65536-entry histogram in TWO dispatches:
//   scan_partial: 32 blocks -> per-chunk totals (bsum, raw)
//   scan_final32: 32 blocks; each computes its base = sum(bsum[i<b])
//                 redundantly (<=31 cached scalar loads) and writes the
//                 scanned histogram. (Folds the old 1-block scan_bsums.)
// rowptr[N]=E is produced by csr_fine (node==N gets running prefix E).
// =====================================================================
__global__ __launch_bounds__(256) void scan_partial(
    const int* __restrict__ cnt, int Ntot, int* __restrict__ bsum)
{
    __shared__ int red[4];
    const int t = threadIdx.x;
    const int base = blockIdx.x * 2048;
    int s = 0;
#pragma unroll
    for (int i = 0; i < 8; ++i) {
        int idx = base + t + i * 256;
        if (idx < Ntot) s += cnt[idx];
    }
#pragma unroll
    for (int off = 32; off >= 1; off >>= 1) s += __shfl_xor(s, off);
    if ((t & 63) == 0) red[t >> 6] = s;
    __syncthreads();
    if (t == 0) bsum[blockIdx.x] = red[0] + red[1] + red[2] + red[3];
}

__global__ __launch_bounds__(256) void scan_final32(
    const int* __restrict__ cnt, int Ntot, const int* __restrict__ bsum,
    int* __restrict__ outp)
{
    __shared__ int sdat[2048];
    __shared__ int tsum[256];
    const int t = threadIdx.x;
    const int base = blockIdx.x * 2048;
    int bbase = 0;
    for (int i = 0; i < blockIdx.x; ++i) bbase += bsum[i];   // redundant, cached
#pragma unroll
    for (int i = 0; i < 8; ++i) {
        int idx = base + t + i * 256;
        sdat[t + i * 256] = (idx < Ntot) ? cnt[idx] : 0;
    }
    __syncthreads();
    int vals[8];
    int s = 0;
#pragma unroll
    for (int j = 0; j < 8; ++j) { vals[j] = sdat[t * 8 + j]; s += vals[j]; }
    tsum[t] = s;
    __syncthreads();
    for (int off = 1; off < 256; off <<= 1) {
        int u = (t >= off) ? tsum[t - off] : 0;
        __syncthreads();
        tsum[t] += u;
        __syncthreads();
    }
    int run = bbase + tsum[t] - s;        // exclusive prefix of this chunk
#pragma unroll
    for (int j = 0; j < 8; ++j) { sdat[t * 8 + j] = run; run += vals[j]; }
    __syncthreads();
#pragma unroll
    for (int i = 0; i < 8; ++i) {
        int idx = base + t + i * 256;
        if (idx < Ntot) outp[idx] = sdat[t + i * 256];
    }
}

// =====================================================================
// MFMA GEMM, B-in-LDS / A-direct (r4 winner, FROZEN).
// Block = 64 rows x BN cols, 256 threads (4 waves).
// =====================================================================
template<int BN, bool ABF16>
__global__ __launch_bounds__(256) void gemm_mfma(
    const void* __restrict__ Avoid, int M,
    const unsigned short* __restrict__ Bt,
    const float* __restrict__ bl, const float* __restrict__ br,
    int dout, unsigned short* __restrict__ XL, unsigned short* __restrict__ XR)
{
    constexpr int LDA = 136;                       // shorts; pad 128+8
    constexpr int NT  = BN / 16;
    __shared__ __attribute__((aligned(16))) unsigned short Bs[BN * LDA];
    const int t  = threadIdx.x;
    const int m0 = blockIdx.x * 64;
    const int n0 = blockIdx.y * BN;

    const int w    = t >> 6;
    const int lane = t & 63;
    const int fr   = lane & 15;
    const int quad = lane >> 4;

    // ---- stage B (BN x 128 bf16 -> LDS), coalesced
#pragma unroll
    for (int i = 0; i < BN / 16; ++i) {
        int c  = t + i * 256;              // short8 chunks
        int n  = c >> 4;                   // 16 chunks per row
        int kc = (c & 15) * 8;
        *(short8*)(Bs + n * LDA + kc) =
            *(const short8*)(Bt + (size_t)(n0 + n) * 128 + kc);
    }

    // ---- load A fragments direct from global (overlaps B staging)
    const int arow = m0 + w * 16 + fr;     // this lane's A row
    const size_t abase = (size_t)(arow < M ? arow : 0) * 128 + quad * 8;
    short8 afr[4];
    if (ABF16) {
        const unsigned short* A = (const unsigned short*)Avoid;
#pragma unroll
        for (int kk = 0; kk < 4; ++kk)
            afr[kk] = *(const short8*)(A + abase + kk * 32);
    } else {
        const float* A = (const float*)Avoid;
#pragma unroll
        for (int kk = 0; kk < 4; ++kk) {
            float4 lo = *(const float4*)(A + abase + kk * 32);
            float4 hi = *(const float4*)(A + abase + kk * 32 + 4);
            afr[kk][0] = (short)f2bf(lo.x); afr[kk][1] = (short)f2bf(lo.y);
            afr[kk][2] = (short)f2bf(lo.z); afr[kk][3] = (short)f2bf(lo.w);
            afr[kk][4] = (short)f2bf(hi.x); afr[kk][5] = (short)f2bf(hi.y);
            afr[kk][6] = (short)f2bf(hi.z); afr[kk][7] = (short)f2bf(hi.w);
        }
    }
    __syncthreads();

    f32x4 acc[NT] = {};
    const unsigned short* bp = Bs + fr * LDA + quad * 8;
#pragma unroll
    for (int kk = 0; kk < 4; ++kk) {
#pragma unroll
        for (int j = 0; j < NT; ++j) {
            short8 bfr = *(const short8*)(bp + j * 16 * LDA + kk * 32);
            acc[j] = __builtin_amdgcn_mfma_f32_16x16x32_bf16(afr[kk], bfr, acc[j], 0, 0, 0);
        }
    }

    // ---- epilogue: +bias, bf16 stores into XL | XR
#pragma unroll
    for (int j = 0; j < NT; ++j) {
        int col = n0 + j * 16 + fr;
        float bias = (col < dout) ? bl[col] : br[col - dout];
#pragma unroll
        for (int r = 0; r < 4; ++r) {
            int row = m0 + w * 16 + quad * 4 + r;
            if (row < M) {
                unsigned short o = f2bf(acc[j][r] + bias);
                if (col < dout) XL[(size_t)row * dout + col] = o;
                else            XR[(size_t)row * dout + (col - dout)] = o;
            }
        }
    }
}

// =====================================================================
// CSR build (atomic-free two-level bucket sort, r5 winner, FROZEN).
// =====================================================================
__global__ __launch_bounds__(256) void csr_scatter(
    const int* __restrict__ src, const int* __restrict__ dst, int E, int tile,
    const int* __restrict__ hist_s, unsigned int* __restrict__ sorted)
{
    __shared__ int cur[256];
    const int t = threadIdx.x, b = blockIdx.x;
    cur[t] = hist_s[t * NBLK + b];
    __syncthreads();
    const int e0 = b * tile;
    const int e1 = min(E, e0 + tile);
    for (int e = e0 + t; e < e1; e += 256) {
        int d = dst[e];
        int pos = atomicAdd(&cur[d >> 8], 1);
        sorted[pos] = ((unsigned int)d << 16) | (unsigned int)src[e];
    }
}

__global__ __launch_bounds__(256) void csr_fine(
    const unsigned int* __restrict__ sorted, int E, int N,
    const int* __restrict__ hist_s,
    int* __restrict__ rowptr, unsigned short* __restrict__ csr_src)
{
    __shared__ int h[256];
    __shared__ int sc[256];
    const int t = threadIdx.x, d = blockIdx.x;
    const int start = hist_s[d * NBLK];
    const int end   = (d < 255) ? hist_s[(d + 1) * NBLK] : E;
    h[t] = 0;
    __syncthreads();
    for (int e = start + t; e < end; e += 256)
        atomicAdd(&h[(sorted[e] >> 16) & 0xFF], 1);
    __syncthreads();
    int v = h[t];
    sc[t] = v;
    __syncthreads();
    for (int off = 1; off < 256; off <<= 1) {
        int u = (t >= off) ? sc[t - off] : 0;
        __syncthreads();
        sc[t] += u;
        __syncthreads();
    }
    const int base = start + sc[t] - v;    // absolute exclusive prefix
    const int node = (d << 8) + t;
    if (node <= N) rowptr[node] = base;    // node==N lands on E exactly
    h[t] = base;                           // absolute cursor
    __syncthreads();
    for (int e = start + t; e < end; e += 256) {
        unsigned int it = sorted[e];
        int pos = atomicAdd(&h[(it >> 16) & 0xFF], 1);
        csr_src[pos] = (unsigned short)(it & 0xFFFFu);
    }
}

// =====================================================================
// Fused GATv2 edge phase (frozen at the gather-fill ceiling ~2.0 TB/s).
// =====================================================================
template<int H>
__global__ __launch_bounds__(256, 4) void gat_fused(
    const unsigned short* __restrict__ xl, const unsigned short* __restrict__ xr,
    const int* __restrict__ rowptr, const unsigned short* __restrict__ csr_src,
    const float* __restrict__ att, const float* __restrict__ bias,
    unsigned short* __restrict__ hout, int hstride, int N)
{
    constexpr int HC  = 32 * H;
    constexpr int LPE = HC / 4;      // lanes per edge (H=4: 32, H=1: 8)
    constexpr int EPW = 64 / LPE;    // edge slots per wave (2 / 8)
    const int node = blockIdx.x * 4 + (threadIdx.x >> 6);
    if (node >= N) return;
    const int lane = threadIdx.x & 63;
    const int q    = lane % LPE;
    const int slot = lane / LPE;
    const int rs   = rowptr[node];
    const int re   = rowptr[node + 1];

    const unsigned short* __restrict__ xlb = xl + 4 * q;
    float4 xri;
    {
        ushort4 u = *(const ushort4*)(xr + (size_t)node * HC + 4 * q);
        xri.x = bf2f(u.x); xri.y = bf2f(u.y); xri.z = bf2f(u.z); xri.w = bf2f(u.w);
    }
    // logit coefs with leaky folded, exp2 domain
    float4 b1, b2;
    {
        float4 a = *(const float4*)(att + 4 * q);
        const float c1 = 0.5f * (1.0f + NEG_SLOPE) * LOG2E;   // 0.6*log2e
        const float c2 = 0.5f * (1.0f - NEG_SLOPE) * LOG2E;   // 0.4*log2e
        b1.x = a.x * c1; b1.y = a.y * c1; b1.z = a.z * c1; b1.w = a.w * c1;
        b2.x = a.x * c2; b2.y = a.y * c2; b2.z = a.z * c2; b2.w = a.w * c2;
    }

    float l = 0.f;
    float4 acc = make_float4(0.f, 0.f, 0.f, 0.f);

    auto ld4 = [&](int s) -> float4 {
        ushort4 u = *(const ushort4*)(xlb + (size_t)s * HC);
        float4 v;
        v.x = bf2f(u.x); v.y = bf2f(u.y); v.z = bf2f(u.z); v.w = bf2f(u.w);
        return v;
    };

    auto edge_w = [&](const float4& v) -> float {   // exp2(att . leakyrelu(v+xri))
        float sx = v.x + xri.x, sy = v.y + xri.y, sz = v.z + xri.z, sw = v.w + xri.w;
        float p  = b1.x * sx;
        float pq = b2.x * fabsf(sx);
        p  = fmaf(b1.y, sy, p);
        pq = fmaf(b2.y, fabsf(sy), pq);
        p  = fmaf(b1.z, sz, p);
        pq = fmaf(b2.z, fabsf(sz), pq);
        p  = fmaf(b1.w, sw, p);
        pq = fmaf(b2.w, fabsf(sw), pq);
        p += pq;
        p = dpp_sum8(p);                 // 8-lane head reduce, VALU pipe
        return exp2f(p);
    };

    // ---- self-loop (src = dst = node), slot 0 only
    if (slot == 0) {
        float4 v = ld4(node);
        float w = edge_w(v);
        l = w;
        acc.x = w * v.x; acc.y = w * v.y; acc.z = w * v.z; acc.w = w * v.w;
    }

    // ---- incoming edges, strided per slot, unrolled x2 (no predication)
    int k = rs + slot;
    for (; k + EPW < re; k += 2 * EPW) {
        int s0 = csr_src[k];
        int s1 = csr_src[k + EPW];
        float4 v0 = ld4(s0);
        float4 v1 = ld4(s1);
        float w0 = edge_w(v0);
        float w1 = edge_w(v1);
        l += w0 + w1;
        acc.x = fmaf(w0, v0.x, fmaf(w1, v1.x, acc.x));
        acc.y = fmaf(w0, v0.y, fmaf(w1, v1.y, acc.y));
        acc.z = fmaf(w0, v0.z, fmaf(w1, v1.z, acc.z));
        acc.w = fmaf(w0, v0.w, fmaf(w1, v1.w, acc.w));
    }
    if (k < re) {
        int s0 = csr_src[k];
        float4 v0 = ld4(s0);
        float w0 = edge_w(v0);
        l += w0;
        acc.x = fmaf(w0, v0.x, acc.x);
        acc.y = fmaf(w0, v0.y, acc.y);
        acc.z = fmaf(w0, v0.z, acc.z);
        acc.w = fmaf(w0, v0.w, acc.w);
    }

    // ---- merge edge slots: plain sums (once per node)
#pragma unroll
    for (int mask = LPE; mask < 64; mask <<= 1) {
        l     += __shfl_xor(l, mask);
        acc.x += __shfl_xor(acc.x, mask);
        acc.y += __shfl_xor(acc.y, mask);
        acc.z += __shfl_xor(acc.z, mask);
        acc.w += __shfl_xor(acc.w, mask);
    }

    if (lane < LPE) {
        const float4 bi = *(const float4*)(bias + 4 * q);
        float inv = 1.f / (l + 1e-16f);
        float4 o;
        o.x = acc.x * inv + bi.x;
        o.y = acc.y * inv + bi.y;
        o.z = acc.z * inv + bi.z;
        o.w = acc.w * inv + bi.w;
        o.x = (o.x > 0.f) ? o.x : expm1f(o.x);
        o.y = (o.y > 0.f) ? o.y : expm1f(o.y);
        o.z = (o.z > 0.f) ? o.z : expm1f(o.z);
        o.w = (o.w > 0.f) ? o.w : expm1f(o.w);
        ushort4 ob;
        ob.x = f2bf(o.x); ob.y = f2bf(o.y); ob.z = f2bf(o.z); ob.w = f2bf(o.w);
        *(ushort4*)(hout + (size_t)node * hstride + 4 * q) = ob;
    }
}

// =====================================================================
// Fused mean-pool + MLP head (h is bf16).
// =====================================================================
__global__ __launch_bounds__(128) void pool_head_kernel(
    const unsigned short* __restrict__ h, int hstride,
    const int* __restrict__ batch, int N,
    const float* __restrict__ meta,
    const float* __restrict__ Wh1, const float* __restrict__ bh1,
    const float* __restrict__ Wh2, const float* __restrict__ bh2,
    float* __restrict__ out)
{
    const int b = blockIdx.x;
    const int t = threadIdx.x;
    __shared__ float s[128];
    __shared__ float z[44];

    int lo = 0, hi = N;
    while (lo < hi) { int mid = (lo + hi) >> 1; if (batch[mid] < b) lo = mid + 1; else hi = mid; }
    int lo2 = lo, hi2 = N;
    while (lo2 < hi2) { int mid = (lo2 + hi2) >> 1; if (batch[mid] < b + 1) lo2 = mid + 1; else hi2 = mid; }
    const int start = lo, end = lo2;

    const int c = t & 31, r = t >> 5;     // 4 rows x 32 channels in flight
    float acc = 0.f;
    for (int row = start + r; row < end; row += 4)
        acc += bf2f(h[(size_t)row * hstride + c]);
    s[t] = acc;
    __syncthreads();
    if (t < 32) {
        float sum = s[t] + s[t + 32] + s[t + 64] + s[t + 96];
        z[t] = sum / fmaxf((float)(end - start), 1.0f);
    } else if (t < 44) {
        z[t] = meta[(size_t)b * 12 + (t - 32)];
    }
    __syncthreads();
    if (t < 32) {
        float hj = bh1[t];
#pragma unroll
        for (int k = 0; k < 44; ++k)
            hj = fmaf(z[k], Wh1[k * 32 + t], hj);
        hj = fmaxf(hj, 0.f);
        float p = hj * Wh2[t];
#pragma unroll
        for (int off = 16; off >= 1; off >>= 1)
            p += __shfl_xor(p, off, 32);
        if (t == 0) out[b] = p + bh2[0];
    }
}

// =====================================================================
extern "C" void kernel_launch(void* const* d_in, const int* in_sizes, int n_in,
                              void* d_out, int out_size, void* d_ws, size_t ws_size,
                              hipStream_t stream)
{
    const float* x     = (const float*)d_in[0];
    const int*   ei    = (const int*)d_in[1];
    const int*   batch = (const int*)d_in[2];
    const float* meta  = (const float*)d_in[3];
    const float* Wl[3]  = {(const float*)d_in[4],  (const float*)d_in[10], (const float*)d_in[16]};
    const float* bl[3]  = {(const float*)d_in[5],  (const float*)d_in[11], (const float*)d_in[17]};
    const float* Wr[3]  = {(const float*)d_in[6],  (const float*)d_in[12], (const float*)d_in[18]};
    const float* br[3]  = {(const float*)d_in[7],  (const float*)d_in[13], (const float*)d_in[19]};
    const float* att[3] = {(const float*)d_in[8],  (const float*)d_in[14], (const float*)d_in[20]};
    const float* bb[3]  = {(const float*)d_in[9],  (const float*)d_in[15], (const float*)d_in[21]};
    const float* Wh1 = (const float*)d_in[22];
    const float* bh1 = (const float*)d_in[23];
    const float* Wh2 = (const float*)d_in[24];
    const float* bh2 = (const float*)d_in[25];
    float* out = (float*)d_out;

    const int N  = in_sizes[0] / 128;
    const int E  = in_sizes[1] / 2;
    const int B  = in_sizes[3] / 12;

    char* wsp = (char*)d_ws;
    size_t off_ = 0;
    auto alloc = [&](size_t bytes) {
        char* p = wsp + off_;
        off_ = (off_ + bytes + 255) & ~(size_t)255;
        return p;
    };
    unsigned short* xlbuf = (unsigned short*)alloc((size_t)N * 128 * 2);  // bf16 gather table
    unsigned short* xrbuf = (unsigned short*)alloc((size_t)N * 128 * 2);  // bf16 xr table
    unsigned short* hbuf  = (unsigned short*)alloc((size_t)N * 128 * 2);  // bf16 layer output
    int*   rowptr  = (int*)alloc((size_t)(N + 1) * 4);
    unsigned short* csr_src = (unsigned short*)alloc((size_t)E * 2);  // src < 65536
    unsigned int*   sorted  = (unsigned int*)alloc((size_t)E * 4);    // (dst<<16)|src, coarse-ordered
    int*   hist_g  = (int*)alloc((size_t)65536 * 4);                  // hist[digit][block]
    int*   hist_s  = (int*)alloc((size_t)65537 * 4);                  // scanned
    unsigned short* Bt0     = (unsigned short*)alloc((size_t)256 * 128 * 2);
    unsigned short* Bt1     = (unsigned short*)alloc((size_t)256 * 128 * 2);
    unsigned short* Bt2     = (unsigned short*)alloc((size_t)64 * 128 * 2);
    int*   bsum    = (int*)alloc((size_t)256 * 4);

    const int* srcI = ei;
    const int* dstI = ei + E;

    // ---- weight prep + CSR coarse hist (fused, one dispatch)
    const int tile = (E + NBLK - 1) / NBLK;
    prep_and_hist<<<288, 256, 0, stream>>>(
        Wl[0], Wr[0], Wl[1], Wr[1], Wl[2], Wr[2], Bt0, Bt1, Bt2,
        dstI, E, tile, hist_g);

    // ---- 2-dispatch scan of the 65536 hist
    scan_partial<<<32, 256, 0, stream>>>(hist_g, 65536, bsum);
    scan_final32<<<32, 256, 0, stream>>>(hist_g, 65536, bsum, hist_s);

    csr_scatter<<<NBLK, 256, 0, stream>>>(srcI, dstI, E, tile, hist_s, sorted);
    csr_fine<<<(N >> 8) + 1, 256, 0, stream>>>(sorted, E, N, hist_s, rowptr, csr_src);

    const int GB = (N + 3) / 4;     // gat_fused blocks (4 nodes / 256-thread block)
    const int MB = (N + 63) / 64;   // gemm row-tiles (BM=64)

    // ---- layer 0 (din=128 f32, H=4, C=32, concat)
    {
        gemm_mfma<128, false><<<dim3(MB, 2), 256, 0, stream>>>(x, N, Bt0, bl[0], br[0], 128, xlbuf, xrbuf);
        gat_fused<4><<<GB, 256, 0, stream>>>(xlbuf, xrbuf, rowptr, csr_src, att[0], bb[0], hbuf, 128, N);
    }
    // ---- layer 1 (din=128 bf16)
    {
        gemm_mfma<128, true><<<dim3(MB, 2), 256, 0, stream>>>(hbuf, N, Bt1, bl[1], br[1], 128, xlbuf, xrbuf);
        gat_fused<4><<<GB, 256, 0, stream>>>(xlbuf, xrbuf, rowptr, csr_src, att[1], bb[1], hbuf, 128, N);
    }
    // ---- layer 2 (H=1, concat=False -> mean over 1 head = identity)
    {
        gemm_mfma<64, true><<<dim3(MB, 1), 256, 0, stream>>>(hbuf, N, Bt2, bl[2], br[2], 32, xlbuf, xrbuf);
        gat_fused<1><<<GB, 256, 0, stream>>>(xlbuf, xrbuf, rowptr, csr_src, att[2], bb[2], hbuf, 32, N);
    }
    // ---- fused global mean pool + head (batch sorted -> binary search, no atomics)
    pool_head_kernel<<<B, 128, 0, stream>>>(hbuf, 32, batch, N, meta, Wh1, bh1, Wh2, bh2, out);
}